// Round 7
// baseline (310.347 us; speedup 1.0000x reference)
//
#include <hip/hip_runtime.h>

namespace {
constexpr int kInCh  = 64;
constexpr int kOutCh = 64;
constexpr int kK     = 3;
constexpr int kFanIn = 8;
constexpr int kH     = 1024;
constexpr int kTileH = 256;          // h per block: 4 per lane via float4
constexpr int kBlk   = 512;          // 8 waves; wave g -> outputs g*8..g*8+7
constexpr int kHB    = kH / kTileH;  // 4 h-tiles per image
}

struct Tap { int rel; float w; };    // rel = ci*kH + dk  (dword offset rel. to row0 + h)

// unaligned-capable 16B vector (dk=+-1 loads are only 4B-aligned)
typedef float f4u __attribute__((ext_vector_type(4), aligned(4)));

// input fake-quant, INTEGER-valued result in [-128,127]. The *0.0625 scale is
// folded into the tap weight (VERIFIED rounds 2-6, absmax=0.0: pow2 scale, fmaf
// fuses the product; chain unchanged). Pure function -> recomputing per use
// (direct-gather) is bit-identical to staging the quantized value.
__device__ __forceinline__ float quant_in_i(float v) {
    float q = rintf(v * 16.0f);
    q = fmaxf(q, -128.0f);
    return fminf(q, 127.0f);
}

// output fake-quant in fp32 (ref conv+quant is fp32; *8 and *0.125 exact pow2)
__device__ __forceinline__ float quant_out(float v) {
    float q = rintf(v * 8.0f);
    q = fmaxf(q, -128.0f);
    q = fminf(q, 127.0f);
    return q * 0.125f;
}

// VERIFIED (absmax=0.0 rounds 1-6): reference == single fp32 FMA chain per output
// in (k-major, ci-minor) tap order. DO NOT change tap ordering or chain structure.
__global__ void prep_taps(const float* __restrict__ weight,
                          const float* __restrict__ mask,
                          Tap* __restrict__ taps,
                          unsigned* __restrict__ dks) {
    __shared__ unsigned long long bal[3];
    __shared__ unsigned sdk;
    const int o    = blockIdx.x;
    const int j    = threadIdx.x;        // key: k*64 + ci  (wave index == k)
    const int k    = j >> 6;
    const int ci   = j & 63;
    const int idx  = (o * kInCh + ci) * kK + k;   // OIH storage

    if (j == 0) sdk = 0u;
    const float m = mask[idx];
    const unsigned long long b = __ballot(m != 0.0f);
    if (ci == 0) bal[k] = b;
    __syncthreads();

    const unsigned long long lower = b & ((1ull << ci) - 1ull);
    int rank = __popcll(lower);
    #pragma unroll
    for (int w = 0; w < kK; ++w) if (w < k) rank += __popcll(bal[w]);

    if (m != 0.0f && rank < kFanIn) {
        taps[o * kFanIn + rank].rel = ci * kH + (k - 1);       // dword offset, includes dk
        taps[o * kFanIn + rank].w   = weight[idx] * m * 0.0625f;
        atomicOr(&sdk, (unsigned)k << (2 * rank));             // record k (dk = k-1)
    }
    // defensive pad (mask guarantees exactly kFanIn ones; ws is poisoned 0xAA)
    int total = __popcll(bal[0]) + __popcll(bal[1]) + __popcll(bal[2]);
    if (j >= total && j < kFanIn) {
        taps[o * kFanIn + j].rel = 0;
        taps[o * kFanIn + j].w   = 0.0f;
        atomicOr(&sdk, 1u << (2 * j));                         // k=1 -> dk=0, benign
    }
    __syncthreads();
    if (j == 0) dks[o] = sdk;
}

// ROUND 7: DIRECT-GATHER, no LDS, no barriers. Evidence R1/R4/R6: three different
// LDS+barrier schedules all land 80-84us (HBM ~3.3TB/s, 50% duty) — per-tile
// period ~10us for 17KB+0.5us work regardless of buffering/prefetch/blocks-per-CU;
// the staged phase structure itself is the cost. Barrier-free streaming kernels
// demonstrably hit 78-85% HBM on this chip (fillBuffer 6.5TB/s here). R5's
// barrier-free attempt failed only because LDS capped it at 8 waves/CU; with no
// LDS we keep 32 waves/CU AND full independence. Tap loads are lane-consecutive
// (coalesced 1KB/wave-instr); cross-output x reuse (~2.7x) absorbed by L1/L2.
template <int EDGE>
__device__ __forceinline__ void conv_body(const float* __restrict__ xn,
                                          const Tap* __restrict__ taps,
                                          const unsigned* __restrict__ dks,
                                          float* __restrict__ outn,
                                          int h0, int g, int lane) {
    const int hb = lane << 2;                 // lane's h offset within tile (float4)
    const float* __restrict__ xr = xn + h0;   // image base + tile origin

    #pragma unroll 1
    for (int oo = 0; oo < 8; ++oo) {
        const int o = g * 8 + oo;
        const Tap* __restrict__ tp = taps + o * kFanIn;   // uniform -> s_load
        const unsigned dk8 = dks[o];                      // uniform -> s_load
        float a0 = 0.f, a1 = 0.f, a2 = 0.f, a3 = 0.f;

        // Single sequential fp32 FMA chain per output element, j ascending
        // (verified order). 4 independent chains (elements of the float4).
        #pragma unroll
        for (int j = 0; j < kFanIn; ++j) {
            const int   rel = tp[j].rel;
            const float w   = tp[j].w;
            f4u v;
            if (EDGE == 0) {
                v = *reinterpret_cast<const f4u*>(xr + rel + hb);
            } else {
                const int dk = (int)((dk8 >> (2 * j)) & 3u) - 1;   // uniform branch
                if (EDGE < 0 && dk == -1) {
                    const bool bad = (hb == 0);            // lane0 elem0: h=-1
                    v = *reinterpret_cast<const f4u*>(xr + rel + hb + (bad ? 1 : 0));
                    if (bad) { v.w = v.z; v.z = v.y; v.y = v.x; v.x = 0.f; }
                } else if (EDGE > 0 && dk == 1) {
                    const bool bad = (hb == kTileH - 4);   // lane63 elem3: h=kH
                    v = *reinterpret_cast<const f4u*>(xr + rel + hb - (bad ? 1 : 0));
                    if (bad) { v.x = v.y; v.y = v.z; v.z = v.w; v.w = 0.f; }
                } else {
                    v = *reinterpret_cast<const f4u*>(xr + rel + hb);
                }
            }
            a0 = fmaf(w, quant_in_i(v.x), a0);
            a1 = fmaf(w, quant_in_i(v.y), a1);
            a2 = fmaf(w, quant_in_i(v.z), a2);
            a3 = fmaf(w, quant_in_i(v.w), a3);
        }
        float4 q = make_float4(quant_out(a0), quant_out(a1), quant_out(a2), quant_out(a3));
        *reinterpret_cast<float4*>(outn + (size_t)o * kH + h0 + hb) = q;   // 16B-aligned
    }
}

__global__ __launch_bounds__(kBlk, 8) void sparse_conv(
        const float* __restrict__ x,
        const Tap*   __restrict__ taps,
        const unsigned* __restrict__ dks,
        float*       __restrict__ out) {
    const int t    = threadIdx.x;
    const int lane = t & 63;
    const int g    = __builtin_amdgcn_readfirstlane(t >> 6);   // wave = o-group (0..7)
    const int hb   = blockIdx.x;                // h-tile (0..3)
    const int n    = blockIdx.y;
    const int h0   = hb * kTileH;
    const float* __restrict__ xn   = x   + (size_t)n * kInCh  * kH;
    float*       __restrict__ outn = out + (size_t)n * kOutCh * kH;

    if (hb == 0)              conv_body<-1>(xn, taps, dks, outn, h0, g, lane);
    else if (hb == kHB - 1)   conv_body< 1>(xn, taps, dks, outn, h0, g, lane);
    else                      conv_body< 0>(xn, taps, dks, outn, h0, g, lane);
}

extern "C" void kernel_launch(void* const* d_in, const int* in_sizes, int n_in,
                              void* d_out, int out_size, void* d_ws, size_t ws_size,
                              hipStream_t stream) {
    const float* x      = (const float*)d_in[0];
    const float* weight = (const float*)d_in[1];
    const float* mask   = (const float*)d_in[2];
    float* out = (float*)d_out;
    Tap*      taps = (Tap*)d_ws;                         // 4 KiB
    unsigned* dks  = (unsigned*)(taps + kOutCh * kFanIn); // +256 B

    const int nBatch = in_sizes[0] / (kInCh * kH);   // 512

    prep_taps<<<kOutCh, kInCh * kK, 0, stream>>>(weight, mask, taps, dks);
    dim3 grid(kHB, nBatch);                          // (4, 512) one-shot blocks
    sparse_conv<<<grid, kBlk, 0, stream>>>(x, taps, dks, out);
}